// Round 15
// baseline (167.747 us; speedup 1.0000x reference)
//
#include <hip/hip_runtime.h>
#include <hip/hip_fp16.h>

#define D 64
#define KMAX 64  // bucket capacity; max in-degree of Poisson(16) graph ~40 (12 sigma to 64)

// ---------------- init: zero the per-dst counters ----------------
__global__ __launch_bounds__(256) void k_zero(int* __restrict__ p, int n4) {
    int stride = gridDim.x * blockDim.x;
    for (int i = blockIdx.x * blockDim.x + threadIdx.x; i < n4; i += stride)
        reinterpret_cast<int4*>(p)[i] = make_int4(0, 0, 0, 0);
}

// ---------------- fused bucket-fill || gemm1 (unscaled) ----------------
// Fill: pos = atomicAdd(&cnt[d],1); csr[d*64+pos] = src; cnt ends as degree
// (hist/scan eliminated). 8-way XCD partition keeps each cnt/csr line owned by
// one XCD L2 (R6-measured: unpartitioned scatter = 64B writeback per 4B store).
__global__ __launch_bounds__(256) void k_fill_gemm(
    const int* __restrict__ src, const int* __restrict__ dst,
    int* __restrict__ cnt, int* __restrict__ csr, int e, int n,
    const float* __restrict__ X, const float* __restrict__ W,
    __half* __restrict__ G, int ntiles, int fill_blocks) {
    __shared__ float Ws[D][D];
    __shared__ float Xs[16][D + 4];

    if (blockIdx.x < fill_blocks) {  // fill path (no LDS, no barriers)
        int r = blockIdx.x & 7;
        int lo = (int)(((long long)r * n) >> 3);
        int hi = (int)(((long long)(r + 1) * n) >> 3);
        int nch = fill_blocks >> 3;
        int chunk = blockIdx.x >> 3;
        for (int i = chunk * blockDim.x + threadIdx.x; i < e; i += nch * blockDim.x) {
            int d = dst[i];
            if (d >= lo && d < hi) {
                int pos = atomicAdd(&cnt[d], 1);
                csr[(d << 6) + pos] = src[i];
            }
        }
        return;
    }

    int tid = threadIdx.x;
    int rl = tid >> 4;
    int c4 = tid & 15;
    int gb = blockIdx.x - fill_blocks;
    int ngb = gridDim.x - fill_blocks;

    for (int i = tid; i < (D * D) / 4; i += 256)
        reinterpret_cast<float4*>(&Ws[0][0])[i] = reinterpret_cast<const float4*>(W)[i];

    for (int tile = gb; tile < ntiles; tile += ngb) {
        int row = tile * 16 + rl;
        __syncthreads();
        {
            float4 v = make_float4(0.f, 0.f, 0.f, 0.f);
            if (row < n) v = reinterpret_cast<const float4*>(X)[(size_t)row * 16 + c4];
            *reinterpret_cast<float4*>(&Xs[rl][c4 * 4]) = v;
        }
        __syncthreads();

        float4 acc = make_float4(0.f, 0.f, 0.f, 0.f);
#pragma unroll
        for (int k = 0; k < D; ++k) {
            float xk = Xs[rl][k];
            float4 w = *reinterpret_cast<const float4*>(&Ws[k][c4 * 4]);
            acc.x += xk * w.x; acc.y += xk * w.y;
            acc.z += xk * w.z; acc.w += xk * w.w;
        }
        if (row < n) {
            __half2 h01 = __floats2half2_rn(acc.x, acc.y);
            __half2 h23 = __floats2half2_rn(acc.z, acc.w);
            int2 packed;
            packed.x = *reinterpret_cast<int*>(&h01);
            packed.y = *reinterpret_cast<int*>(&h23);
            reinterpret_cast<int2*>(G)[(size_t)row * 16 + c4] = packed;
        }
    }
}

// ---------------- fused agg1 + batched gemm2 ----------------
// Per tile of 32 rows: each of 4 waves gathers 8 rows sequentially (quarter-
// wave per edge, dinv on the fly from cnt), relu+b1, into wave-private
// xs[32][64]; then the R12-proven batched GEMM (acc[8], Ws reads amortized
// over 8 rows -- R9's 1-row-per-wave fusion was LDS-issue-bound). x never
// touches HBM. (256,4) cap + partial unroll: R11 lesson, else VGPR=256.
__global__ __launch_bounds__(256, 4) void k_agg_gemm2(
    const __half* __restrict__ G1, const int* __restrict__ cnt,
    const int* __restrict__ csr, const float* __restrict__ b1,
    const float* __restrict__ W2, __half* __restrict__ G2, int n, int ntiles) {
    __shared__ float Ws[D][D];   // 16 KB
    __shared__ float xs[32][D];  // 8 KB
    int tid = threadIdx.x;
    int wv = tid >> 6;
    int lane = tid & 63;
    int eq = lane >> 4;
    int c4 = lane & 15;

    for (int i = tid; i < (D * D) / 4; i += 256)
        reinterpret_cast<float4*>(&Ws[0][0])[i] = reinterpret_cast<const float4*>(W2)[i];

    for (int tile = blockIdx.x; tile < ntiles; tile += gridDim.x) {
        int rowbase = tile * 32;

        // ---- gather phase: 8 rows per wave into xs (wave-private)
        for (int j = 0; j < 8; ++j) {
            int wid = rowbase + (wv << 3) + j;
            float4 o = make_float4(0.f, 0.f, 0.f, 0.f);
            if (wid < n) {
                int deg = cnt[wid];
                int beg = wid << 6;
                int end = beg + deg;
                float4 acc = make_float4(0.f, 0.f, 0.f, 0.f);
                for (int e = beg + eq; e < end; e += 4) {
                    int s = __builtin_nontemporal_load(&csr[e]);
                    float ds = rsqrtf((float)(cnt[s] + 1));
                    int2 raw = reinterpret_cast<const int2*>(G1)[(size_t)s * 16 + c4];
                    __half2 p0 = *reinterpret_cast<__half2*>(&raw.x);
                    __half2 p1 = *reinterpret_cast<__half2*>(&raw.y);
                    float2 f0 = __half22float2(p0);
                    float2 f1 = __half22float2(p1);
                    acc.x += ds * f0.x; acc.y += ds * f0.y;
                    acc.z += ds * f1.x; acc.w += ds * f1.y;
                }
#pragma unroll
                for (int off = 16; off < 64; off <<= 1) {
                    acc.x += __shfl_xor(acc.x, off);
                    acc.y += __shfl_xor(acc.y, off);
                    acc.z += __shfl_xor(acc.z, off);
                    acc.w += __shfl_xor(acc.w, off);
                }
                float dv = rsqrtf((float)(deg + 1));
                int2 raw = reinterpret_cast<const int2*>(G1)[(size_t)wid * 16 + c4];
                __half2 p0 = *reinterpret_cast<__half2*>(&raw.x);
                __half2 p1 = *reinterpret_cast<__half2*>(&raw.y);
                float2 f0 = __half22float2(p0);
                float2 f1 = __half22float2(p1);
                float4 b4 = reinterpret_cast<const float4*>(b1)[c4];
                o.x = fmaxf((acc.x + dv * f0.x) * dv + b4.x, 0.f);
                o.y = fmaxf((acc.y + dv * f0.y) * dv + b4.y, 0.f);
                o.z = fmaxf((acc.z + dv * f1.x) * dv + b4.z, 0.f);
                o.w = fmaxf((acc.w + dv * f1.y) * dv + b4.w, 0.f);
            }
            if (eq == 0) *reinterpret_cast<float4*>(&xs[(wv << 3) + j][c4 * 4]) = o;
        }

        __syncthreads();  // Ws staged (first tile); uniform across block

        // ---- batched GEMM: each wave computes its own 8 rows (xs wave-private)
        float acc[8];
#pragma unroll
        for (int j = 0; j < 8; ++j) acc[j] = 0.f;
#pragma unroll 4
        for (int k4 = 0; k4 < D; k4 += 4) {
            float w0 = Ws[k4 + 0][lane];
            float w1 = Ws[k4 + 1][lane];
            float w2 = Ws[k4 + 2][lane];
            float w3 = Ws[k4 + 3][lane];
#pragma unroll
            for (int j = 0; j < 8; ++j) {
                float4 xv = *reinterpret_cast<const float4*>(&xs[(wv << 3) + j][k4]);
                acc[j] += xv.x * w0 + xv.y * w1 + xv.z * w2 + xv.w * w3;
            }
        }
#pragma unroll
        for (int j = 0; j < 8; ++j) {
            int r = rowbase + (wv << 3) + j;
            if (r < n) G2[(size_t)r * D + lane] = __float2half(acc[j]);
        }
        __syncthreads();  // xs consumed before next tile overwrites (cheap: ~2 tiles/block)
    }
}

// ---------------- agg2 -> out ----------------
__global__ __launch_bounds__(256) void k_agg2(const __half* __restrict__ G,
                                              const int* __restrict__ cnt,
                                              const int* __restrict__ csr,
                                              const float* __restrict__ bias,
                                              float* __restrict__ out, int n) {
    int wid = (blockIdx.x * blockDim.x + threadIdx.x) >> 6;
    if (wid >= n) return;
    int lane = threadIdx.x & 63;
    int eq = lane >> 4;
    int c4 = lane & 15;
    int deg = cnt[wid];
    int beg = wid << 6;
    int end = beg + deg;

    float4 acc = make_float4(0.f, 0.f, 0.f, 0.f);
    for (int e = beg + eq; e < end; e += 4) {
        int s = __builtin_nontemporal_load(&csr[e]);
        float ds = rsqrtf((float)(cnt[s] + 1));
        int2 raw = reinterpret_cast<const int2*>(G)[(size_t)s * 16 + c4];
        __half2 p0 = *reinterpret_cast<__half2*>(&raw.x);
        __half2 p1 = *reinterpret_cast<__half2*>(&raw.y);
        float2 f0 = __half22float2(p0);
        float2 f1 = __half22float2(p1);
        acc.x += ds * f0.x; acc.y += ds * f0.y;
        acc.z += ds * f1.x; acc.w += ds * f1.y;
    }
#pragma unroll
    for (int off = 16; off < 64; off <<= 1) {
        acc.x += __shfl_xor(acc.x, off);
        acc.y += __shfl_xor(acc.y, off);
        acc.z += __shfl_xor(acc.z, off);
        acc.w += __shfl_xor(acc.w, off);
    }
    if (eq == 0) {
        float dv = rsqrtf((float)(deg + 1));
        int2 raw = reinterpret_cast<const int2*>(G)[(size_t)wid * 16 + c4];
        __half2 p0 = *reinterpret_cast<__half2*>(&raw.x);
        __half2 p1 = *reinterpret_cast<__half2*>(&raw.y);
        float2 f0 = __half22float2(p0);
        float2 f1 = __half22float2(p1);
        float4 b4 = reinterpret_cast<const float4*>(bias)[c4];
        float4 o;
        o.x = (acc.x + dv * f0.x) * dv + b4.x;
        o.y = (acc.y + dv * f0.y) * dv + b4.y;
        o.z = (acc.z + dv * f1.x) * dv + b4.z;
        o.w = (acc.w + dv * f1.y) * dv + b4.w;
        reinterpret_cast<float4*>(out)[(size_t)wid * 16 + c4] = o;
    }
}

// ---------------- launch ----------------

extern "C" void kernel_launch(void* const* d_in, const int* in_sizes, int n_in,
                              void* d_out, int out_size, void* d_ws, size_t ws_size,
                              hipStream_t stream) {
    const int* ei = (const int*)d_in[0];
    const float* emb = (const float*)d_in[1];
    const float* W1 = (const float*)d_in[2];
    const float* b1 = (const float*)d_in[3];
    const float* W2 = (const float*)d_in[4];
    const float* b2 = (const float*)d_in[5];
    float* out = (float*)d_out;

    int E = in_sizes[0] / 2;
    int N = in_sizes[1] / D;
    const int* src = ei;
    const int* dst = ei + E;

    auto al = [](size_t v) { return (v + 255) & ~(size_t)255; };
    char* ws = (char*)d_ws;
    size_t off = 0;
    int* cnt = (int*)(ws + off);      off = al(off + (size_t)N * 4);
    int* csr = (int*)(ws + off);      off = al(off + (size_t)N * KMAX * 4);  // 12.8 MB
    __half* g1 = (__half*)(ws + off); off = al(off + (size_t)N * D * 2);
    __half* g2 = (__half*)(ws + off); off = al(off + (size_t)N * D * 2);

    int ntiles16 = (N + 15) / 16;
    int ntiles32 = (N + 31) / 32;
    int fill_blocks = 1024;
    int gemm_blocks = 1024;
    int row_blocks = (N + 3) / 4;

    hipLaunchKernelGGL(k_zero, dim3(512), dim3(256), 0, stream, cnt, (N + 3) / 4);
    hipLaunchKernelGGL(k_fill_gemm, dim3(fill_blocks + gemm_blocks), dim3(256), 0, stream,
                       src, dst, cnt, csr, E, N, emb, W1, g1, ntiles16, fill_blocks);
    hipLaunchKernelGGL(k_agg_gemm2, dim3(1024), dim3(256), 0, stream,
                       g1, cnt, csr, b1, W2, g2, N, ntiles32);
    hipLaunchKernelGGL(k_agg2, dim3(row_blocks), dim3(256), 0, stream,
                       g2, cnt, csr, b2, out, N);
}

// Round 17
// 129.104 us; speedup vs baseline: 1.2993x; 1.2993x over previous
//
#include <hip/hip_runtime.h>
#include <hip/hip_fp16.h>

#define D 64
#define KMAX 64  // bucket capacity; max in-degree of Poisson(16) graph ~40 (12 sigma to 64)

// ---------------- init: zero the per-dst counters ----------------
__global__ __launch_bounds__(256) void k_zero(int* __restrict__ p, int n4) {
    int stride = gridDim.x * blockDim.x;
    for (int i = blockIdx.x * blockDim.x + threadIdx.x; i < n4; i += stride)
        reinterpret_cast<int4*>(p)[i] = make_int4(0, 0, 0, 0);
}

// ---------------- fused bucket-fill || gemm1 (unscaled) ----------------
// Fill: pos = atomicAdd(&cnt[d],1); csr[d*64+pos] = src; cnt ends as degree
// (hist/scan eliminated, R14: 183->140us). 8-way XCD partition keeps each
// cnt/csr line owned by one XCD L2 (R6: unpartitioned = 64B writeback/4B store).
// Grid = 1536 total: 24KB LDS -> 6 blocks/CU x 256 CU; 2048 left a straggler
// wave of 512 blocks.
__global__ __launch_bounds__(256) void k_fill_gemm(
    const int* __restrict__ src, const int* __restrict__ dst,
    int* __restrict__ cnt, int* __restrict__ csr, int e, int n,
    const float* __restrict__ X, const float* __restrict__ W,
    __half* __restrict__ G, int ntiles, int fill_blocks) {
    __shared__ float Ws[D][D];
    __shared__ float Xs[16][D + 4];

    if (blockIdx.x < fill_blocks) {  // fill path (no LDS, no barriers)
        int r = blockIdx.x & 7;
        int lo = (int)(((long long)r * n) >> 3);
        int hi = (int)(((long long)(r + 1) * n) >> 3);
        int nch = fill_blocks >> 3;
        int chunk = blockIdx.x >> 3;
        for (int i = chunk * blockDim.x + threadIdx.x; i < e; i += nch * blockDim.x) {
            int d = dst[i];
            if (d >= lo && d < hi) {
                int pos = atomicAdd(&cnt[d], 1);
                csr[(d << 6) + pos] = src[i];
            }
        }
        return;
    }

    int tid = threadIdx.x;
    int rl = tid >> 4;
    int c4 = tid & 15;
    int gb = blockIdx.x - fill_blocks;
    int ngb = gridDim.x - fill_blocks;

    for (int i = tid; i < (D * D) / 4; i += 256)
        reinterpret_cast<float4*>(&Ws[0][0])[i] = reinterpret_cast<const float4*>(W)[i];

    for (int tile = gb; tile < ntiles; tile += ngb) {
        int row = tile * 16 + rl;
        __syncthreads();
        {
            float4 v = make_float4(0.f, 0.f, 0.f, 0.f);
            if (row < n) v = reinterpret_cast<const float4*>(X)[(size_t)row * 16 + c4];
            *reinterpret_cast<float4*>(&Xs[rl][c4 * 4]) = v;
        }
        __syncthreads();

        float4 acc = make_float4(0.f, 0.f, 0.f, 0.f);
#pragma unroll
        for (int k = 0; k < D; ++k) {
            float xk = Xs[rl][k];
            float4 w = *reinterpret_cast<const float4*>(&Ws[k][c4 * 4]);
            acc.x += xk * w.x; acc.y += xk * w.y;
            acc.z += xk * w.z; acc.w += xk * w.w;
        }
        if (row < n) {
            __half2 h01 = __floats2half2_rn(acc.x, acc.y);
            __half2 h23 = __floats2half2_rn(acc.z, acc.w);
            int2 packed;
            packed.x = *reinterpret_cast<int*>(&h01);
            packed.y = *reinterpret_cast<int*>(&h23);
            reinterpret_cast<int2*>(G)[(size_t)row * 16 + c4] = packed;
        }
    }
}

// ---------------- agg: out = dinv_i*(Σ_s dinv_s*G[s] + dinv_i*G[i]) + b ------
// One wave per row; 16-lane group eq loads its 4 edge indices with ONE int4
// (bucket is 16B-aligned), then issues the 4 (cnt,G) gather pairs back-to-back
// (independent -> 4x MLP; the old scalar loop serialized csr->G per edge).
// Tail slots predicated: s clamped to 0 (hot line), weight 0.
template <bool RELU>
__global__ __launch_bounds__(256) void k_agg(const __half* __restrict__ G,
                                             const int* __restrict__ cnt,
                                             const int* __restrict__ csr,
                                             const float* __restrict__ bias,
                                             float* __restrict__ out, int n) {
    int wid = (blockIdx.x * blockDim.x + threadIdx.x) >> 6;
    if (wid >= n) return;
    int lane = threadIdx.x & 63;
    int eq = lane >> 4;
    int c4 = lane & 15;
    int deg = cnt[wid];
    const int4* bucket = reinterpret_cast<const int4*>(csr + (wid << 6));

    float4 acc = make_float4(0.f, 0.f, 0.f, 0.f);
    // quad q covers edge slots [4q, 4q+4); group eq takes quads eq, eq+4, ...
    for (int q = eq; q * 4 < deg; q += 4) {
        int4 sv = bucket[q];
        int nvalid = deg - q * 4;  // >= 1 here
        int sidx[4] = {sv.x, sv.y, sv.z, sv.w};
#pragma unroll
        for (int j = 0; j < 4; ++j) {
            bool v = (j < nvalid);
            int s = v ? sidx[j] : 0;
            float ds = v ? rsqrtf((float)(cnt[s] + 1)) : 0.f;
            int2 raw = reinterpret_cast<const int2*>(G)[(size_t)s * 16 + c4];
            __half2 p0 = *reinterpret_cast<__half2*>(&raw.x);
            __half2 p1 = *reinterpret_cast<__half2*>(&raw.y);
            float2 f0 = __half22float2(p0);
            float2 f1 = __half22float2(p1);
            acc.x += ds * f0.x; acc.y += ds * f0.y;
            acc.z += ds * f1.x; acc.w += ds * f1.y;
        }
    }
#pragma unroll
    for (int off = 16; off < 64; off <<= 1) {
        acc.x += __shfl_xor(acc.x, off);
        acc.y += __shfl_xor(acc.y, off);
        acc.z += __shfl_xor(acc.z, off);
        acc.w += __shfl_xor(acc.w, off);
    }
    if (eq == 0) {
        float dv = rsqrtf((float)(deg + 1));
        int2 raw = reinterpret_cast<const int2*>(G)[(size_t)wid * 16 + c4];
        __half2 p0 = *reinterpret_cast<__half2*>(&raw.x);
        __half2 p1 = *reinterpret_cast<__half2*>(&raw.y);
        float2 f0 = __half22float2(p0);
        float2 f1 = __half22float2(p1);
        float4 b4 = reinterpret_cast<const float4*>(bias)[c4];
        float4 o;
        o.x = (acc.x + dv * f0.x) * dv + b4.x;
        o.y = (acc.y + dv * f0.y) * dv + b4.y;
        o.z = (acc.z + dv * f1.x) * dv + b4.z;
        o.w = (acc.w + dv * f1.y) * dv + b4.w;
        if (RELU) {
            o.x = fmaxf(o.x, 0.f); o.y = fmaxf(o.y, 0.f);
            o.z = fmaxf(o.z, 0.f); o.w = fmaxf(o.w, 0.f);
        }
        reinterpret_cast<float4*>(out)[(size_t)wid * 16 + c4] = o;
    }
}

// ---------------- gemm2b: batched x@W2 -> g2 fp16 UNSCALED ----------------
// R12-proven: (256,4) cap + partial unroll keeps VGPR <=128 (compiler hits
// 256 VGPR / 8.5% occupancy without it).
__global__ __launch_bounds__(256, 4) void k_gemm2b(const float* __restrict__ X,
                                                   const float* __restrict__ W,
                                                   __half* __restrict__ G, int n, int ntiles) {
    __shared__ float Ws[D][D];
    __shared__ float Xs[32][D];
    int tid = threadIdx.x;
    int col = tid & 63;
    int rq = tid >> 6;

    for (int i = tid; i < (D * D) / 4; i += 256)
        reinterpret_cast<float4*>(&Ws[0][0])[i] = reinterpret_cast<const float4*>(W)[i];

    for (int tile = blockIdx.x; tile < ntiles; tile += gridDim.x) {
        int rowbase = tile * 32;
        __syncthreads();
        if (rowbase + 32 <= n) {
            const float4* xp = reinterpret_cast<const float4*>(X + (size_t)rowbase * D);
            for (int i = tid; i < (32 * D) / 4; i += 256)
                reinterpret_cast<float4*>(&Xs[0][0])[i] = xp[i];
        } else {
            for (int i = tid; i < 32 * D; i += 256) {
                int r = rowbase + (i >> 6);
                Xs[i >> 6][i & 63] = (r < n) ? X[(size_t)r * D + (i & 63)] : 0.f;
            }
        }
        __syncthreads();

        float acc[8];
#pragma unroll
        for (int j = 0; j < 8; ++j) acc[j] = 0.f;
#pragma unroll 4
        for (int k4 = 0; k4 < D; k4 += 4) {
            float w0 = Ws[k4 + 0][col];
            float w1 = Ws[k4 + 1][col];
            float w2 = Ws[k4 + 2][col];
            float w3 = Ws[k4 + 3][col];
#pragma unroll
            for (int j = 0; j < 8; ++j) {
                float4 xv = *reinterpret_cast<const float4*>(&Xs[(rq << 3) + j][k4]);
                acc[j] += xv.x * w0 + xv.y * w1 + xv.z * w2 + xv.w * w3;
            }
        }
#pragma unroll
        for (int j = 0; j < 8; ++j) {
            int r = rowbase + (rq << 3) + j;
            if (r < n) G[(size_t)r * D + col] = __float2half(acc[j]);
        }
    }
}

// ---------------- launch ----------------

extern "C" void kernel_launch(void* const* d_in, const int* in_sizes, int n_in,
                              void* d_out, int out_size, void* d_ws, size_t ws_size,
                              hipStream_t stream) {
    const int* ei = (const int*)d_in[0];
    const float* emb = (const float*)d_in[1];
    const float* W1 = (const float*)d_in[2];
    const float* b1 = (const float*)d_in[3];
    const float* W2 = (const float*)d_in[4];
    const float* b2 = (const float*)d_in[5];
    float* out = (float*)d_out;

    int E = in_sizes[0] / 2;
    int N = in_sizes[1] / D;
    const int* src = ei;
    const int* dst = ei + E;

    auto al = [](size_t v) { return (v + 255) & ~(size_t)255; };
    char* ws = (char*)d_ws;
    size_t off = 0;
    int* cnt = (int*)(ws + off);      off = al(off + (size_t)N * 4);
    int* csr = (int*)(ws + off);      off = al(off + (size_t)N * KMAX * 4);  // 12.8 MB
    __half* g1 = (__half*)(ws + off); off = al(off + (size_t)N * D * 2);
    float* x = (float*)(ws + off);    off = al(off + (size_t)N * D * 4);
    __half* g2 = (__half*)(ws + off); off = al(off + (size_t)N * D * 2);

    int ntiles16 = (N + 15) / 16;
    int ntiles32 = (N + 31) / 32;
    int fill_blocks = 1024;
    int gemm_blocks = 512;  // total 1536 = 6 blocks/CU x 256 CU (24KB LDS limit)
    int row_blocks = (N + 3) / 4;

    hipLaunchKernelGGL(k_zero, dim3(512), dim3(256), 0, stream, cnt, (N + 3) / 4);
    hipLaunchKernelGGL(k_fill_gemm, dim3(fill_blocks + gemm_blocks), dim3(256), 0, stream,
                       src, dst, cnt, csr, E, N, emb, W1, g1, ntiles16, fill_blocks);
    hipLaunchKernelGGL(k_agg<true>, dim3(row_blocks), dim3(256), 0, stream,
                       g1, cnt, csr, b1, x, N);
    hipLaunchKernelGGL(k_gemm2b, dim3(1024), dim3(256), 0, stream,
                       x, W2, g2, N, ntiles32);
    hipLaunchKernelGGL(k_agg<false>, dim3(row_blocks), dim3(256), 0, stream,
                       g2, cnt, csr, b2, out, N);
}

// Round 18
// 120.405 us; speedup vs baseline: 1.3932x; 1.0722x over previous
//
#include <hip/hip_runtime.h>
#include <hip/hip_fp16.h>

#define D 64
#define KMAX 64  // bucket capacity; max in-degree of Poisson(16) graph ~40 (12 sigma to 64)

// ---------------- init: zero the per-dst counters ----------------
__global__ __launch_bounds__(256) void k_zero(int* __restrict__ p, int n4) {
    int stride = gridDim.x * blockDim.x;
    for (int i = blockIdx.x * blockDim.x + threadIdx.x; i < n4; i += stride)
        reinterpret_cast<int4*>(p)[i] = make_int4(0, 0, 0, 0);
}

// ---------------- fused bucket-fill || gemm1 (unscaled) ----------------
// Fill: pos = atomicAdd(&cnt[d],1); csr[d*64+pos] = src; cnt ends as degree
// (hist/scan eliminated, R14: 183->140us). 8-way XCD partition keeps each
// cnt/csr line owned by one XCD L2 (R6: unpartitioned = 64B writeback/4B store).
// Grid = 1536 = 6 blocks/CU x 256 CU (24KB LDS) -- fully co-resident (R17).
__global__ __launch_bounds__(256) void k_fill_gemm(
    const int* __restrict__ src, const int* __restrict__ dst,
    int* __restrict__ cnt, int* __restrict__ csr, int e, int n,
    const float* __restrict__ X, const float* __restrict__ W,
    __half* __restrict__ G, int ntiles, int fill_blocks) {
    __shared__ float Ws[D][D];
    __shared__ float Xs[16][D + 4];

    if (blockIdx.x < fill_blocks) {  // fill path (no LDS, no barriers)
        int r = blockIdx.x & 7;
        int lo = (int)(((long long)r * n) >> 3);
        int hi = (int)(((long long)(r + 1) * n) >> 3);
        int nch = fill_blocks >> 3;
        int chunk = blockIdx.x >> 3;
        for (int i = chunk * blockDim.x + threadIdx.x; i < e; i += nch * blockDim.x) {
            int d = dst[i];
            if (d >= lo && d < hi) {
                int pos = atomicAdd(&cnt[d], 1);
                csr[(d << 6) + pos] = src[i];
            }
        }
        return;
    }

    int tid = threadIdx.x;
    int rl = tid >> 4;
    int c4 = tid & 15;
    int gb = blockIdx.x - fill_blocks;
    int ngb = gridDim.x - fill_blocks;

    for (int i = tid; i < (D * D) / 4; i += 256)
        reinterpret_cast<float4*>(&Ws[0][0])[i] = reinterpret_cast<const float4*>(W)[i];

    for (int tile = gb; tile < ntiles; tile += ngb) {
        int row = tile * 16 + rl;
        __syncthreads();
        {
            float4 v = make_float4(0.f, 0.f, 0.f, 0.f);
            if (row < n) v = reinterpret_cast<const float4*>(X)[(size_t)row * 16 + c4];
            *reinterpret_cast<float4*>(&Xs[rl][c4 * 4]) = v;
        }
        __syncthreads();

        float4 acc = make_float4(0.f, 0.f, 0.f, 0.f);
#pragma unroll
        for (int k = 0; k < D; ++k) {
            float xk = Xs[rl][k];
            float4 w = *reinterpret_cast<const float4*>(&Ws[k][c4 * 4]);
            acc.x += xk * w.x; acc.y += xk * w.y;
            acc.z += xk * w.z; acc.w += xk * w.w;
        }
        if (row < n) {
            __half2 h01 = __floats2half2_rn(acc.x, acc.y);
            __half2 h23 = __floats2half2_rn(acc.z, acc.w);
            int2 packed;
            packed.x = *reinterpret_cast<int*>(&h01);
            packed.y = *reinterpret_cast<int*>(&h23);
            reinterpret_cast<int2*>(G)[(size_t)row * 16 + c4] = packed;
        }
    }
}

// ---------------- agg1: x = fp16(relu(dinv_i*(Σ ds*g1[s] + dv*g1[i]) + b1)) --
// One wave per row; 16-lane group loads 4 edge indices with one int4, then
// issues the 4 (cnt,G) gather pairs back-to-back (4x MLP, R17: 140->129us).
__global__ __launch_bounds__(256) void k_agg1(const __half* __restrict__ G,
                                              const int* __restrict__ cnt,
                                              const int* __restrict__ csr,
                                              const float* __restrict__ bias,
                                              __half* __restrict__ x, int n) {
    int wid = (blockIdx.x * blockDim.x + threadIdx.x) >> 6;
    if (wid >= n) return;
    int lane = threadIdx.x & 63;
    int eq = lane >> 4;
    int c4 = lane & 15;
    int deg = cnt[wid];
    const int4* bucket = reinterpret_cast<const int4*>(csr + (wid << 6));

    float4 acc = make_float4(0.f, 0.f, 0.f, 0.f);
    for (int q = eq; q * 4 < deg; q += 4) {
        int4 sv = bucket[q];
        int nvalid = deg - q * 4;
        int sidx[4] = {sv.x, sv.y, sv.z, sv.w};
#pragma unroll
        for (int j = 0; j < 4; ++j) {
            bool v = (j < nvalid);
            int s = v ? sidx[j] : 0;
            float ds = v ? rsqrtf((float)(cnt[s] + 1)) : 0.f;
            int2 raw = reinterpret_cast<const int2*>(G)[(size_t)s * 16 + c4];
            __half2 p0 = *reinterpret_cast<__half2*>(&raw.x);
            __half2 p1 = *reinterpret_cast<__half2*>(&raw.y);
            float2 f0 = __half22float2(p0);
            float2 f1 = __half22float2(p1);
            acc.x += ds * f0.x; acc.y += ds * f0.y;
            acc.z += ds * f1.x; acc.w += ds * f1.y;
        }
    }
#pragma unroll
    for (int off = 16; off < 64; off <<= 1) {
        acc.x += __shfl_xor(acc.x, off);
        acc.y += __shfl_xor(acc.y, off);
        acc.z += __shfl_xor(acc.z, off);
        acc.w += __shfl_xor(acc.w, off);
    }
    if (eq == 0) {
        float dv = rsqrtf((float)(deg + 1));
        int2 raw = reinterpret_cast<const int2*>(G)[(size_t)wid * 16 + c4];
        __half2 p0 = *reinterpret_cast<__half2*>(&raw.x);
        __half2 p1 = *reinterpret_cast<__half2*>(&raw.y);
        float2 f0 = __half22float2(p0);
        float2 f1 = __half22float2(p1);
        float4 b4 = reinterpret_cast<const float4*>(bias)[c4];
        float ox = fmaxf((acc.x + dv * f0.x) * dv + b4.x, 0.f);
        float oy = fmaxf((acc.y + dv * f0.y) * dv + b4.y, 0.f);
        float oz = fmaxf((acc.z + dv * f1.x) * dv + b4.z, 0.f);
        float ow = fmaxf((acc.w + dv * f1.y) * dv + b4.w, 0.f);
        __half2 h01 = __floats2half2_rn(ox, oy);
        __half2 h23 = __floats2half2_rn(oz, ow);
        int2 packed;
        packed.x = *reinterpret_cast<int*>(&h01);
        packed.y = *reinterpret_cast<int*>(&h23);
        reinterpret_cast<int2*>(x)[(size_t)wid * 16 + c4] = packed;
    }
}

// ---------------- gemm2b: g2' = dinv_r * (x @ W2), fp16 in / fp16 out -------
// x staged fp16->fp32 into LDS (8B/lane int2 loads, coalesced). Epilogue
// pre-scales by dinv_r (cnt complete here) so agg2 needs NO per-edge cnt
// gather. R12-proven (256,4) cap + partial unroll keeps VGPR <=128.
__global__ __launch_bounds__(256, 4) void k_gemm2b(const __half* __restrict__ X,
                                                   const float* __restrict__ W,
                                                   const int* __restrict__ cnt,
                                                   __half* __restrict__ G, int n, int ntiles) {
    __shared__ float Ws[D][D];
    __shared__ float Xs[32][D];
    int tid = threadIdx.x;
    int col = tid & 63;
    int rq = tid >> 6;

    for (int i = tid; i < (D * D) / 4; i += 256)
        reinterpret_cast<float4*>(&Ws[0][0])[i] = reinterpret_cast<const float4*>(W)[i];

    for (int tile = blockIdx.x; tile < ntiles; tile += gridDim.x) {
        int rowbase = tile * 32;
        __syncthreads();
        // stage 32 fp16 rows -> fp32 LDS; i indexes 4-half groups (32*16 = 512)
        for (int i = tid; i < 32 * 16; i += 256) {
            int rr = rowbase + (i >> 4);
            int p = i & 15;
            float4 f = make_float4(0.f, 0.f, 0.f, 0.f);
            if (rr < n) {
                int2 raw = reinterpret_cast<const int2*>(X)[(size_t)rr * 16 + p];
                __half2 h0 = *reinterpret_cast<__half2*>(&raw.x);
                __half2 h1 = *reinterpret_cast<__half2*>(&raw.y);
                float2 f0 = __half22float2(h0);
                float2 f1 = __half22float2(h1);
                f = make_float4(f0.x, f0.y, f1.x, f1.y);
            }
            *reinterpret_cast<float4*>(&Xs[i >> 4][p * 4]) = f;
        }
        __syncthreads();

        float acc[8];
#pragma unroll
        for (int j = 0; j < 8; ++j) acc[j] = 0.f;
#pragma unroll 4
        for (int k4 = 0; k4 < D; k4 += 4) {
            float w0 = Ws[k4 + 0][col];
            float w1 = Ws[k4 + 1][col];
            float w2 = Ws[k4 + 2][col];
            float w3 = Ws[k4 + 3][col];
#pragma unroll
            for (int j = 0; j < 8; ++j) {
                float4 xv = *reinterpret_cast<const float4*>(&Xs[(rq << 3) + j][k4]);
                acc[j] += xv.x * w0 + xv.y * w1 + xv.z * w2 + xv.w * w3;
            }
        }
#pragma unroll
        for (int j = 0; j < 8; ++j) {
            int r = rowbase + (rq << 3) + j;
            if (r < n) {
                float dv = rsqrtf((float)(cnt[r] + 1));
                G[(size_t)r * D + col] = __float2half(acc[j] * dv);
            }
        }
    }
}

// ---------------- agg2: out = dinv_i*(Σ g2'[s] + g2'[i]) + b2 (pre-scaled) --
__global__ __launch_bounds__(256) void k_agg2(const __half* __restrict__ G,
                                              const int* __restrict__ cnt,
                                              const int* __restrict__ csr,
                                              const float* __restrict__ bias,
                                              float* __restrict__ out, int n) {
    int wid = (blockIdx.x * blockDim.x + threadIdx.x) >> 6;
    if (wid >= n) return;
    int lane = threadIdx.x & 63;
    int eq = lane >> 4;
    int c4 = lane & 15;
    int deg = cnt[wid];
    const int4* bucket = reinterpret_cast<const int4*>(csr + (wid << 6));

    float4 acc = make_float4(0.f, 0.f, 0.f, 0.f);
    for (int q = eq; q * 4 < deg; q += 4) {
        int4 sv = bucket[q];
        int nvalid = deg - q * 4;
        int sidx[4] = {sv.x, sv.y, sv.z, sv.w};
#pragma unroll
        for (int j = 0; j < 4; ++j) {
            bool v = (j < nvalid);
            int s = v ? sidx[j] : 0;
            float wgt = v ? 1.f : 0.f;
            int2 raw = reinterpret_cast<const int2*>(G)[(size_t)s * 16 + c4];
            __half2 p0 = *reinterpret_cast<__half2*>(&raw.x);
            __half2 p1 = *reinterpret_cast<__half2*>(&raw.y);
            float2 f0 = __half22float2(p0);
            float2 f1 = __half22float2(p1);
            acc.x += wgt * f0.x; acc.y += wgt * f0.y;
            acc.z += wgt * f1.x; acc.w += wgt * f1.y;
        }
    }
#pragma unroll
    for (int off = 16; off < 64; off <<= 1) {
        acc.x += __shfl_xor(acc.x, off);
        acc.y += __shfl_xor(acc.y, off);
        acc.z += __shfl_xor(acc.z, off);
        acc.w += __shfl_xor(acc.w, off);
    }
    if (eq == 0) {
        float dv = rsqrtf((float)(deg + 1));
        int2 raw = reinterpret_cast<const int2*>(G)[(size_t)wid * 16 + c4];
        __half2 p0 = *reinterpret_cast<__half2*>(&raw.x);
        __half2 p1 = *reinterpret_cast<__half2*>(&raw.y);
        float2 f0 = __half22float2(p0);
        float2 f1 = __half22float2(p1);
        float4 b4 = reinterpret_cast<const float4*>(bias)[c4];
        float4 o;
        o.x = (acc.x + f0.x) * dv + b4.x;
        o.y = (acc.y + f0.y) * dv + b4.y;
        o.z = (acc.z + f1.x) * dv + b4.z;
        o.w = (acc.w + f1.y) * dv + b4.w;
        reinterpret_cast<float4*>(out)[(size_t)wid * 16 + c4] = o;
    }
}

// ---------------- launch ----------------

extern "C" void kernel_launch(void* const* d_in, const int* in_sizes, int n_in,
                              void* d_out, int out_size, void* d_ws, size_t ws_size,
                              hipStream_t stream) {
    const int* ei = (const int*)d_in[0];
    const float* emb = (const float*)d_in[1];
    const float* W1 = (const float*)d_in[2];
    const float* b1 = (const float*)d_in[3];
    const float* W2 = (const float*)d_in[4];
    const float* b2 = (const float*)d_in[5];
    float* out = (float*)d_out;

    int E = in_sizes[0] / 2;
    int N = in_sizes[1] / D;
    const int* src = ei;
    const int* dst = ei + E;

    auto al = [](size_t v) { return (v + 255) & ~(size_t)255; };
    char* ws = (char*)d_ws;
    size_t off = 0;
    int* cnt = (int*)(ws + off);      off = al(off + (size_t)N * 4);
    int* csr = (int*)(ws + off);      off = al(off + (size_t)N * KMAX * 4);  // 12.8 MB
    __half* g1 = (__half*)(ws + off); off = al(off + (size_t)N * D * 2);
    __half* x = (__half*)(ws + off);  off = al(off + (size_t)N * D * 2);
    __half* g2 = (__half*)(ws + off); off = al(off + (size_t)N * D * 2);

    int ntiles16 = (N + 15) / 16;
    int ntiles32 = (N + 31) / 32;
    int fill_blocks = 1024;
    int gemm_blocks = 512;  // total 1536 = 6 blocks/CU x 256 CU (24KB LDS limit)
    int row_blocks = (N + 3) / 4;

    hipLaunchKernelGGL(k_zero, dim3(512), dim3(256), 0, stream, cnt, (N + 3) / 4);
    hipLaunchKernelGGL(k_fill_gemm, dim3(fill_blocks + gemm_blocks), dim3(256), 0, stream,
                       src, dst, cnt, csr, E, N, emb, W1, g1, ntiles16, fill_blocks);
    hipLaunchKernelGGL(k_agg1, dim3(row_blocks), dim3(256), 0, stream,
                       g1, cnt, csr, b1, x, N);
    hipLaunchKernelGGL(k_gemm2b, dim3(1024), dim3(256), 0, stream,
                       x, W2, cnt, g2, N, ntiles32);
    hipLaunchKernelGGL(k_agg2, dim3(row_blocks), dim3(256), 0, stream,
                       g2, cnt, csr, b2, out, N);
}

// Round 19
// 120.242 us; speedup vs baseline: 1.3951x; 1.0014x over previous
//
#include <hip/hip_runtime.h>
#include <hip/hip_fp16.h>

#define D 64
#define KMAX 64  // bucket capacity; max in-degree of Poisson(16) graph ~40 (12 sigma to 64)

// ---------------- init: zero the per-dst counters ----------------
__global__ __launch_bounds__(256) void k_zero(int* __restrict__ p, int n4) {
    int stride = gridDim.x * blockDim.x;
    for (int i = blockIdx.x * blockDim.x + threadIdx.x; i < n4; i += stride)
        reinterpret_cast<int4*>(p)[i] = make_int4(0, 0, 0, 0);
}

// ---------------- fused bucket-fill || gemm1 (unscaled) ----------------
// Fill: pos = atomicAdd(&cnt[d],1); csr[d*64+pos] = src; cnt ends as degree
// (hist/scan eliminated, R14). 8-way XCD partition keeps each cnt/csr line
// owned by one XCD L2 (R6: unpartitioned = 64B writeback per 4B store).
// R19: dst read as int2 (2 edges/thread/iter -> 2x MLP on the atomic chain);
// fill:gemm = 1152:384 so both sides co-terminate (was 1024:512, gemm idled).
__global__ __launch_bounds__(256) void k_fill_gemm(
    const int* __restrict__ src, const int* __restrict__ dst,
    int* __restrict__ cnt, int* __restrict__ csr, int e, int n,
    const float* __restrict__ X, const float* __restrict__ W,
    __half* __restrict__ G, int ntiles, int fill_blocks) {
    __shared__ float Ws[D][D];
    __shared__ float Xs[16][D + 4];

    if (blockIdx.x < fill_blocks) {  // fill path (no LDS, no barriers)
        int r = blockIdx.x & 7;
        int lo = (int)(((long long)r * n) >> 3);
        int hi = (int)(((long long)(r + 1) * n) >> 3);
        int nch = fill_blocks >> 3;
        int chunk = blockIdx.x >> 3;
        int tid = threadIdx.x;
        int npairs = e >> 1;
        for (int i = chunk * 256 + tid; i < npairs; i += nch * 256) {
            int2 d2 = reinterpret_cast<const int2*>(dst)[i];
            if (d2.x >= lo && d2.x < hi) {
                int pos = atomicAdd(&cnt[d2.x], 1);
                csr[(d2.x << 6) + pos] = src[2 * i];
            }
            if (d2.y >= lo && d2.y < hi) {
                int pos = atomicAdd(&cnt[d2.y], 1);
                csr[(d2.y << 6) + pos] = src[2 * i + 1];
            }
        }
        if ((e & 1) && chunk == 0 && tid == 0) {  // odd tail, once per range
            int d = dst[e - 1];
            if (d >= lo && d < hi) {
                int pos = atomicAdd(&cnt[d], 1);
                csr[(d << 6) + pos] = src[e - 1];
            }
        }
        return;
    }

    int tid = threadIdx.x;
    int rl = tid >> 4;
    int c4 = tid & 15;
    int gb = blockIdx.x - fill_blocks;
    int ngb = gridDim.x - fill_blocks;

    for (int i = tid; i < (D * D) / 4; i += 256)
        reinterpret_cast<float4*>(&Ws[0][0])[i] = reinterpret_cast<const float4*>(W)[i];

    for (int tile = gb; tile < ntiles; tile += ngb) {
        int row = tile * 16 + rl;
        __syncthreads();
        {
            float4 v = make_float4(0.f, 0.f, 0.f, 0.f);
            if (row < n) v = reinterpret_cast<const float4*>(X)[(size_t)row * 16 + c4];
            *reinterpret_cast<float4*>(&Xs[rl][c4 * 4]) = v;
        }
        __syncthreads();

        float4 acc = make_float4(0.f, 0.f, 0.f, 0.f);
#pragma unroll
        for (int k = 0; k < D; ++k) {
            float xk = Xs[rl][k];
            float4 w = *reinterpret_cast<const float4*>(&Ws[k][c4 * 4]);
            acc.x += xk * w.x; acc.y += xk * w.y;
            acc.z += xk * w.z; acc.w += xk * w.w;
        }
        if (row < n) {
            __half2 h01 = __floats2half2_rn(acc.x, acc.y);
            __half2 h23 = __floats2half2_rn(acc.z, acc.w);
            int2 packed;
            packed.x = *reinterpret_cast<int*>(&h01);
            packed.y = *reinterpret_cast<int*>(&h23);
            reinterpret_cast<int2*>(G)[(size_t)row * 16 + c4] = packed;
        }
    }
}

// ---------------- agg1: x = fp16(relu(dinv_i*(Σ ds*g1[s] + dv*g1[i]) + b1)) --
// One wave per row; 16-lane group loads 4 edge indices with one int4, then
// issues the 4 (cnt,G) gather pairs back-to-back (4x MLP, R17: 140->129us).
__global__ __launch_bounds__(256) void k_agg1(const __half* __restrict__ G,
                                              const int* __restrict__ cnt,
                                              const int* __restrict__ csr,
                                              const float* __restrict__ bias,
                                              __half* __restrict__ x, int n) {
    int wid = (blockIdx.x * blockDim.x + threadIdx.x) >> 6;
    if (wid >= n) return;
    int lane = threadIdx.x & 63;
    int eq = lane >> 4;
    int c4 = lane & 15;
    int deg = cnt[wid];
    const int4* bucket = reinterpret_cast<const int4*>(csr + (wid << 6));

    float4 acc = make_float4(0.f, 0.f, 0.f, 0.f);
    for (int q = eq; q * 4 < deg; q += 4) {
        int4 sv = bucket[q];
        int nvalid = deg - q * 4;
        int sidx[4] = {sv.x, sv.y, sv.z, sv.w};
#pragma unroll
        for (int j = 0; j < 4; ++j) {
            bool v = (j < nvalid);
            int s = v ? sidx[j] : 0;
            float ds = v ? rsqrtf((float)(cnt[s] + 1)) : 0.f;
            int2 raw = reinterpret_cast<const int2*>(G)[(size_t)s * 16 + c4];
            __half2 p0 = *reinterpret_cast<__half2*>(&raw.x);
            __half2 p1 = *reinterpret_cast<__half2*>(&raw.y);
            float2 f0 = __half22float2(p0);
            float2 f1 = __half22float2(p1);
            acc.x += ds * f0.x; acc.y += ds * f0.y;
            acc.z += ds * f1.x; acc.w += ds * f1.y;
        }
    }
#pragma unroll
    for (int off = 16; off < 64; off <<= 1) {
        acc.x += __shfl_xor(acc.x, off);
        acc.y += __shfl_xor(acc.y, off);
        acc.z += __shfl_xor(acc.z, off);
        acc.w += __shfl_xor(acc.w, off);
    }
    if (eq == 0) {
        float dv = rsqrtf((float)(deg + 1));
        int2 raw = reinterpret_cast<const int2*>(G)[(size_t)wid * 16 + c4];
        __half2 p0 = *reinterpret_cast<__half2*>(&raw.x);
        __half2 p1 = *reinterpret_cast<__half2*>(&raw.y);
        float2 f0 = __half22float2(p0);
        float2 f1 = __half22float2(p1);
        float4 b4 = reinterpret_cast<const float4*>(bias)[c4];
        float ox = fmaxf((acc.x + dv * f0.x) * dv + b4.x, 0.f);
        float oy = fmaxf((acc.y + dv * f0.y) * dv + b4.y, 0.f);
        float oz = fmaxf((acc.z + dv * f1.x) * dv + b4.z, 0.f);
        float ow = fmaxf((acc.w + dv * f1.y) * dv + b4.w, 0.f);
        __half2 h01 = __floats2half2_rn(ox, oy);
        __half2 h23 = __floats2half2_rn(oz, ow);
        int2 packed;
        packed.x = *reinterpret_cast<int*>(&h01);
        packed.y = *reinterpret_cast<int*>(&h23);
        reinterpret_cast<int2*>(x)[(size_t)wid * 16 + c4] = packed;
    }
}

// ---------------- gemm2b: g2' = dinv_r * (x @ W2), fp16 in / fp16 out -------
// x staged fp16->fp32 into LDS (8B/lane int2 loads, coalesced). Epilogue
// pre-scales by dinv_r (cnt complete here) so agg2 needs NO per-edge cnt
// gather (R18: 129->120us). (256,4) cap + partial unroll keeps VGPR <=128.
__global__ __launch_bounds__(256, 4) void k_gemm2b(const __half* __restrict__ X,
                                                   const float* __restrict__ W,
                                                   const int* __restrict__ cnt,
                                                   __half* __restrict__ G, int n, int ntiles) {
    __shared__ float Ws[D][D];
    __shared__ float Xs[32][D];
    int tid = threadIdx.x;
    int col = tid & 63;
    int rq = tid >> 6;

    for (int i = tid; i < (D * D) / 4; i += 256)
        reinterpret_cast<float4*>(&Ws[0][0])[i] = reinterpret_cast<const float4*>(W)[i];

    for (int tile = blockIdx.x; tile < ntiles; tile += gridDim.x) {
        int rowbase = tile * 32;
        __syncthreads();
        for (int i = tid; i < 32 * 16; i += 256) {
            int rr = rowbase + (i >> 4);
            int p = i & 15;
            float4 f = make_float4(0.f, 0.f, 0.f, 0.f);
            if (rr < n) {
                int2 raw = reinterpret_cast<const int2*>(X)[(size_t)rr * 16 + p];
                __half2 h0 = *reinterpret_cast<__half2*>(&raw.x);
                __half2 h1 = *reinterpret_cast<__half2*>(&raw.y);
                float2 f0 = __half22float2(h0);
                float2 f1 = __half22float2(h1);
                f = make_float4(f0.x, f0.y, f1.x, f1.y);
            }
            *reinterpret_cast<float4*>(&Xs[i >> 4][p * 4]) = f;
        }
        __syncthreads();

        float acc[8];
#pragma unroll
        for (int j = 0; j < 8; ++j) acc[j] = 0.f;
#pragma unroll 4
        for (int k4 = 0; k4 < D; k4 += 4) {
            float w0 = Ws[k4 + 0][col];
            float w1 = Ws[k4 + 1][col];
            float w2 = Ws[k4 + 2][col];
            float w3 = Ws[k4 + 3][col];
#pragma unroll
            for (int j = 0; j < 8; ++j) {
                float4 xv = *reinterpret_cast<const float4*>(&Xs[(rq << 3) + j][k4]);
                acc[j] += xv.x * w0 + xv.y * w1 + xv.z * w2 + xv.w * w3;
            }
        }
#pragma unroll
        for (int j = 0; j < 8; ++j) {
            int r = rowbase + (rq << 3) + j;
            if (r < n) {
                float dv = rsqrtf((float)(cnt[r] + 1));
                G[(size_t)r * D + col] = __float2half(acc[j] * dv);
            }
        }
    }
}

// ---------------- agg2: out = dinv_i*(Σ g2'[s] + g2'[i]) + b2 (pre-scaled) --
__global__ __launch_bounds__(256) void k_agg2(const __half* __restrict__ G,
                                              const int* __restrict__ cnt,
                                              const int* __restrict__ csr,
                                              const float* __restrict__ bias,
                                              float* __restrict__ out, int n) {
    int wid = (blockIdx.x * blockDim.x + threadIdx.x) >> 6;
    if (wid >= n) return;
    int lane = threadIdx.x & 63;
    int eq = lane >> 4;
    int c4 = lane & 15;
    int deg = cnt[wid];
    const int4* bucket = reinterpret_cast<const int4*>(csr + (wid << 6));

    float4 acc = make_float4(0.f, 0.f, 0.f, 0.f);
    for (int q = eq; q * 4 < deg; q += 4) {
        int4 sv = bucket[q];
        int nvalid = deg - q * 4;
        int sidx[4] = {sv.x, sv.y, sv.z, sv.w};
#pragma unroll
        for (int j = 0; j < 4; ++j) {
            bool v = (j < nvalid);
            int s = v ? sidx[j] : 0;
            float wgt = v ? 1.f : 0.f;
            int2 raw = reinterpret_cast<const int2*>(G)[(size_t)s * 16 + c4];
            __half2 p0 = *reinterpret_cast<__half2*>(&raw.x);
            __half2 p1 = *reinterpret_cast<__half2*>(&raw.y);
            float2 f0 = __half22float2(p0);
            float2 f1 = __half22float2(p1);
            acc.x += wgt * f0.x; acc.y += wgt * f0.y;
            acc.z += wgt * f1.x; acc.w += wgt * f1.y;
        }
    }
#pragma unroll
    for (int off = 16; off < 64; off <<= 1) {
        acc.x += __shfl_xor(acc.x, off);
        acc.y += __shfl_xor(acc.y, off);
        acc.z += __shfl_xor(acc.z, off);
        acc.w += __shfl_xor(acc.w, off);
    }
    if (eq == 0) {
        float dv = rsqrtf((float)(deg + 1));
        int2 raw = reinterpret_cast<const int2*>(G)[(size_t)wid * 16 + c4];
        __half2 p0 = *reinterpret_cast<__half2*>(&raw.x);
        __half2 p1 = *reinterpret_cast<__half2*>(&raw.y);
        float2 f0 = __half22float2(p0);
        float2 f1 = __half22float2(p1);
        float4 b4 = reinterpret_cast<const float4*>(bias)[c4];
        float4 o;
        o.x = (acc.x + f0.x) * dv + b4.x;
        o.y = (acc.y + f0.y) * dv + b4.y;
        o.z = (acc.z + f1.x) * dv + b4.z;
        o.w = (acc.w + f1.y) * dv + b4.w;
        reinterpret_cast<float4*>(out)[(size_t)wid * 16 + c4] = o;
    }
}

// ---------------- launch ----------------

extern "C" void kernel_launch(void* const* d_in, const int* in_sizes, int n_in,
                              void* d_out, int out_size, void* d_ws, size_t ws_size,
                              hipStream_t stream) {
    const int* ei = (const int*)d_in[0];
    const float* emb = (const float*)d_in[1];
    const float* W1 = (const float*)d_in[2];
    const float* b1 = (const float*)d_in[3];
    const float* W2 = (const float*)d_in[4];
    const float* b2 = (const float*)d_in[5];
    float* out = (float*)d_out;

    int E = in_sizes[0] / 2;
    int N = in_sizes[1] / D;
    const int* src = ei;
    const int* dst = ei + E;

    auto al = [](size_t v) { return (v + 255) & ~(size_t)255; };
    char* ws = (char*)d_ws;
    size_t off = 0;
    int* cnt = (int*)(ws + off);      off = al(off + (size_t)N * 4);
    int* csr = (int*)(ws + off);      off = al(off + (size_t)N * KMAX * 4);  // 12.8 MB
    __half* g1 = (__half*)(ws + off); off = al(off + (size_t)N * D * 2);
    __half* x = (__half*)(ws + off);  off = al(off + (size_t)N * D * 2);
    __half* g2 = (__half*)(ws + off); off = al(off + (size_t)N * D * 2);

    int ntiles16 = (N + 15) / 16;
    int ntiles32 = (N + 31) / 32;
    int fill_blocks = 1152;  // 8 ranges x 144 chunks
    int gemm_blocks = 384;   // total 1536 = 6 blocks/CU x 256 CU (24KB LDS limit)
    int row_blocks = (N + 3) / 4;

    hipLaunchKernelGGL(k_zero, dim3(512), dim3(256), 0, stream, cnt, (N + 3) / 4);
    hipLaunchKernelGGL(k_fill_gemm, dim3(fill_blocks + gemm_blocks), dim3(256), 0, stream,
                       src, dst, cnt, csr, E, N, emb, W1, g1, ntiles16, fill_blocks);
    hipLaunchKernelGGL(k_agg1, dim3(row_blocks), dim3(256), 0, stream,
                       g1, cnt, csr, b1, x, N);
    hipLaunchKernelGGL(k_gemm2b, dim3(1024), dim3(256), 0, stream,
                       x, W2, cnt, g2, N, ntiles32);
    hipLaunchKernelGGL(k_agg2, dim3(row_blocks), dim3(256), 0, stream,
                       g2, cnt, csr, b2, out, N);
}